// Round 7
// baseline (391.903 us; speedup 1.0000x reference)
//
#include <hip/hip_runtime.h>

typedef unsigned short u16;
typedef unsigned int u32;
typedef __attribute__((ext_vector_type(8))) short bf16x8;   // 8 bf16 in 4 VGPRs
typedef __attribute__((ext_vector_type(4))) float f32x4;
typedef __attribute__((ext_vector_type(4))) u16 u16x4;

typedef __attribute__((address_space(1))) unsigned int as1_u32;
typedef __attribute__((address_space(3))) unsigned int as3_u32;

#define SEQ 4096
#define HID 1024
#define NHEAD 16
#define BATCH 2

__device__ __forceinline__ u16 f2b(float f) {
  union { float f; u32 u; } v; v.f = f;
  u32 r = v.u + 0x7FFFu + ((v.u >> 16) & 1u);   // RNE
  return (u16)(r >> 16);
}

__device__ __forceinline__ float b2f(u16 b) {
  union { u32 u; float f; } v; v.u = ((u32)b) << 16;
  return v.f;
}

__device__ __forceinline__ void async_cp16(const void* g, void* l) {
  __builtin_amdgcn_global_load_lds((const as1_u32*)g, (as3_u32*)l, 16, 0, 0);
}

// ---------------- fp32 -> bf16 convert (all 7 tensors, one launch) ----------------
__global__ __launch_bounds__(256) void cvt_all(
    const float* __restrict__ q, const float* __restrict__ k, const float* __restrict__ v,
    const float* __restrict__ Wq, const float* __restrict__ Wk,
    const float* __restrict__ Wv, const float* __restrict__ Wo,
    u16* __restrict__ xq, u16* __restrict__ xk, u16* __restrict__ xv,
    u16* __restrict__ wq, u16* __restrict__ wk, u16* __restrict__ wv, u16* __restrict__ wo) {
  const int total = (3 << 21) + (4 << 18);   // 7,340,032 float4 groups
  for (int i = blockIdx.x * blockDim.x + threadIdx.x; i < total; i += gridDim.x * blockDim.x) {
    const float* src; u16* dst; int j;
    if (i < (3 << 21)) {
      const int sel = i >> 21; j = i & ((1 << 21) - 1);
      src = sel == 0 ? q : (sel == 1 ? k : v);
      dst = sel == 0 ? xq : (sel == 1 ? xk : xv);
    } else {
      const int ii = i - (3 << 21);
      const int sel = ii >> 18; j = ii & ((1 << 18) - 1);
      src = sel == 0 ? Wq : (sel == 1 ? Wk : (sel == 2 ? Wv : Wo));
      dst = sel == 0 ? wq : (sel == 1 ? wk : (sel == 2 ? wv : wo));
    }
    float4 f = ((const float4*)src)[j];
    u16x4 o; o.x = f2b(f.x); o.y = f2b(f.y); o.z = f2b(f.z); o.w = f2b(f.w);
    ((u16x4*)dst)[j] = o;
  }
}

// ---------------- GEMM core: C = A[8192x1024] * Bw[1024x1024]^T + bias ----------------
// BK=64 staged as two m97-style BK=32 panels per barrier round (halves barrier count).
// Panel stride = 4096 u16 ELEMENTS (128 rows x 32 cols) — r6 bug was 8192 here.
// MODE 0: bf16 row-major out (operand-SWAPPED mfma -> vectorized row stores)
// MODE 1: fp32 row-major out (swapped, float4 stores)
// MODE 2: bf16 transposed out -> vT[(b*16+h)*64+d][token] (unswapped: regs = tokens)
template <int MODE>
__device__ __forceinline__ void gemm_core(
    const u16* __restrict__ A, const u16* __restrict__ Bw,
    const float* __restrict__ bias, void* __restrict__ Cout,
    u16* As, u16* Bs, long brow, long bcol) {
  const int K = HID, N = HID;
  const int tid = threadIdx.x;
  const int lane = tid & 63;
  const int wave = tid >> 6;
  const int l15 = lane & 15;
  const int quad = lane >> 4;
  const int wr = wave >> 1;
  const int wc = wave & 1;

  const int srow = lane >> 2;          // row within 16-row chunk (1 KB per cp16)
  const int scol = (lane & 3) * 8;     // bf16 elems (16B per lane)

  // 4 staging chunks per wave per matrix: j = (panel<<1)|sub
  const u16* Ag[4]; const u16* Bg[4]; u16* Al[4]; u16* Bl[4];
#pragma unroll
  for (int j = 0; j < 4; ++j) {
    const int sub = j & 1, pan = j >> 1;
    const long roff = (wave + 4 * sub) * 16 + srow;
    const long coff = pan * 32 + scol;
    Ag[j] = A + (brow + roff) * (long)K + coff;
    Bg[j] = Bw + (bcol + roff) * (long)K + coff;
    Al[j] = As + pan * 4096 + (wave + 4 * sub) * 512;
    Bl[j] = Bs + pan * 4096 + (wave + 4 * sub) * 512;
  }

  f32x4 acc[4][4];
#pragma unroll
  for (int i = 0; i < 4; ++i)
#pragma unroll
    for (int j = 0; j < 4; ++j) acc[i][j] = f32x4{0.f, 0.f, 0.f, 0.f};

  const u16* Afb = As + (wr * 64 + l15) * 32 + quad * 8;
  const u16* Bfb = Bs + (wc * 64 + l15) * 32 + quad * 8;

  for (int k0 = 0; k0 < K; k0 += 64) {
#pragma unroll
    for (int j = 0; j < 4; ++j) {
      async_cp16(Ag[j] + k0, Al[j]);
      async_cp16(Bg[j] + k0, Bl[j]);
    }
    __syncthreads();
#pragma unroll
    for (int kh = 0; kh < 2; ++kh) {
      bf16x8 af[4], bfv[4];
#pragma unroll
      for (int mt = 0; mt < 4; ++mt) af[mt] = *(const bf16x8*)(Afb + kh * 4096 + mt * 512);
#pragma unroll
      for (int nt = 0; nt < 4; ++nt) bfv[nt] = *(const bf16x8*)(Bfb + kh * 4096 + nt * 512);
#pragma unroll
      for (int mt = 0; mt < 4; ++mt)
#pragma unroll
        for (int nt = 0; nt < 4; ++nt) {
          if (MODE == 2)
            acc[mt][nt] = __builtin_amdgcn_mfma_f32_16x16x32_bf16(af[mt], bfv[nt], acc[mt][nt], 0, 0, 0);
          else  // swapped: D^T -> cols(N) on quad/reg, rows(M) on l15
            acc[mt][nt] = __builtin_amdgcn_mfma_f32_16x16x32_bf16(bfv[nt], af[mt], acc[mt][nt], 0, 0, 0);
        }
    }
    __syncthreads();
  }

  const long crow0 = brow + wr * 64;
  const long ccol0 = bcol + wc * 64;

  if (MODE == 2) {
    // acc[mt][nt][r] = C[token = crow0+mt*16+quad*4+r][hid = ccol0+nt*16+l15]
#pragma unroll
    for (int nt = 0; nt < 4; ++nt) {
      const long col = ccol0 + nt * 16 + l15;
      const float bv = bias[col];
#pragma unroll
      for (int mt = 0; mt < 4; ++mt) {
        const long tokbase = crow0 + mt * 16 + quad * 4;  // 4 consecutive tokens
        const long b = tokbase >> 12;
        const long tok = tokbase & 4095;
        u16x4 pk;
        pk.x = f2b(acc[mt][nt][0] + bv);
        pk.y = f2b(acc[mt][nt][1] + bv);
        pk.z = f2b(acc[mt][nt][2] + bv);
        pk.w = f2b(acc[mt][nt][3] + bv);
        *(u16x4*)((u16*)Cout + (b * 1024 + col) * (long)SEQ + tok) = pk;
      }
    }
  } else {
    // swapped: acc[mt][nt][r] = C[crow0+mt*16+l15][ccol0+nt*16+quad*4+r]
#pragma unroll
    for (int nt = 0; nt < 4; ++nt) {
      const long colb = ccol0 + nt * 16 + quad * 4;
      const float4 b4 = *(const float4*)(bias + colb);
#pragma unroll
      for (int mt = 0; mt < 4; ++mt) {
        const long row = crow0 + mt * 16 + l15;
        if (MODE == 1) {
          float4 v;
          v.x = acc[mt][nt][0] + b4.x;
          v.y = acc[mt][nt][1] + b4.y;
          v.z = acc[mt][nt][2] + b4.z;
          v.w = acc[mt][nt][3] + b4.w;
          *(float4*)((float*)Cout + row * (long)N + colb) = v;
        } else {
          u16x4 pk;
          pk.x = f2b(acc[mt][nt][0] + b4.x);
          pk.y = f2b(acc[mt][nt][1] + b4.y);
          pk.z = f2b(acc[mt][nt][2] + b4.z);
          pk.w = f2b(acc[mt][nt][3] + b4.w);
          *(u16x4*)((u16*)Cout + row * (long)N + colb) = pk;
        }
      }
    }
  }
}

struct Gemm3Args {
  const u16* A[3]; const u16* W[3]; const float* bias[3]; void* C[3]; int mode[3];
};

__global__ __launch_bounds__(256, 2) void gemm_bt_fused(Gemm3Args ga) {
  __shared__ __align__(16) u16 As[2 * 128 * 32];   // 16 KB (2 panels of 4096 elems)
  __shared__ __align__(16) u16 Bs[2 * 128 * 32];   // 16 KB
  const int z = blockIdx.z;
  const long brow = (long)blockIdx.y * 128;
  const long bcol = (long)blockIdx.x * 128;
  if (ga.mode[z] == 2)
    gemm_core<2>(ga.A[z], ga.W[z], ga.bias[z], ga.C[z], As, Bs, brow, bcol);
  else
    gemm_core<0>(ga.A[z], ga.W[z], ga.bias[z], ga.C[z], As, Bs, brow, bcol);
}

// ---------------- windowed attention ----------------
// block = (b, window, head-group of 4, row-half). wave = one head, 32 query rows.
// grid = 2*64*4*2 = 1024 blocks. Swapped-operand MFMA throughout.
__global__ __launch_bounds__(256, 4) void attn_win(
    const u16* __restrict__ qp, const u16* __restrict__ kp,
    const u16* __restrict__ vT, u16* __restrict__ attended,
    float* __restrict__ Psum) {
  __shared__ __align__(16) u16 Plds[4][32][72];    // per-wave P (bf16) [query][key]

  const int tid = threadIdx.x;
  const int lane = tid & 63;
  const int wave = tid >> 6;
  const int l15 = lane & 15;
  const int quad = lane >> 4;

  const int idx = blockIdx.x;          // (((b*64+n)*4)+hg)*2 + half
  const int half = idx & 1;
  const int hg = (idx >> 1) & 3;
  const int wn = idx >> 3;
  const int b = wn >> 6;
  const int n = wn & 63;
  const int h = hg * 4 + wave;

  const long qrow0 = (long)b * SEQ + (long)n * 64 + half * 32;  // 32 query rows
  const long krow0 = (long)b * SEQ + (long)n * 64;              // all 64 key rows
  const long cbase = (long)h * 64;

  u16(*Pw)[72] = Plds[wave];

  // --- S' = (K Q^T): s[mt][nt][reg]: key = nt*16+quad*4+reg, query = mt*16+l15 ---
  f32x4 s[2][4];
#pragma unroll
  for (int i = 0; i < 2; ++i)
#pragma unroll
    for (int j = 0; j < 4; ++j) s[i][j] = f32x4{0.f, 0.f, 0.f, 0.f};
#pragma unroll
  for (int kt = 0; kt < 2; ++kt) {
    bf16x8 aq[2], bkf[4];
#pragma unroll
    for (int mt = 0; mt < 2; ++mt)
      aq[mt] = *(const bf16x8*)(qp + (qrow0 + mt * 16 + l15) * HID + cbase + kt * 32 + quad * 8);
#pragma unroll
    for (int nt = 0; nt < 4; ++nt)
      bkf[nt] = *(const bf16x8*)(kp + (krow0 + nt * 16 + l15) * HID + cbase + kt * 32 + quad * 8);
#pragma unroll
    for (int mt = 0; mt < 2; ++mt)
#pragma unroll
      for (int nt = 0; nt < 4; ++nt)
        s[mt][nt] = __builtin_amdgcn_mfma_f32_16x16x32_bf16(bkf[nt], aq[mt], s[mt][nt], 0, 0, 0);
  }

  // --- softmax over 64 keys: 16 in-lane values (nt x reg) + quad reduce ---
#pragma unroll
  for (int mt = 0; mt < 2; ++mt) {
    float m = -1e30f;
#pragma unroll
    for (int nt = 0; nt < 4; ++nt)
#pragma unroll
      for (int r = 0; r < 4; ++r) { s[mt][nt][r] *= 0.125f; m = fmaxf(m, s[mt][nt][r]); }
    m = fmaxf(m, __shfl_xor(m, 16));
    m = fmaxf(m, __shfl_xor(m, 32));
    float sum = 0.f;
#pragma unroll
    for (int nt = 0; nt < 4; ++nt)
#pragma unroll
      for (int r = 0; r < 4; ++r) { float e = __expf(s[mt][nt][r] - m); s[mt][nt][r] = e; sum += e; }
    sum += __shfl_xor(sum, 16);
    sum += __shfl_xor(sum, 32);
    const float inv = 1.f / sum;
#pragma unroll
    for (int nt = 0; nt < 4; ++nt)
#pragma unroll
      for (int r = 0; r < 4; ++r) s[mt][nt][r] *= inv;
  }

  // --- stash P (bf16) [query][key], vectorized u16x4 writes ---
#pragma unroll
  for (int mt = 0; mt < 2; ++mt)
#pragma unroll
    for (int nt = 0; nt < 4; ++nt) {
      u16x4 pk;
      pk.x = f2b(s[mt][nt][0]);
      pk.y = f2b(s[mt][nt][1]);
      pk.z = f2b(s[mt][nt][2]);
      pk.w = f2b(s[mt][nt][3]);
      *(u16x4*)(&Pw[mt * 16 + l15][nt * 16 + quad * 4]) = pk;
    }

  // --- O' = (V^T P^T): o[mt][nt][reg]: d = nt*16+quad*4+reg, token = mt*16+l15 ---
  f32x4 o[2][4];
#pragma unroll
  for (int i = 0; i < 2; ++i)
#pragma unroll
    for (int j = 0; j < 4; ++j) o[i][j] = f32x4{0.f, 0.f, 0.f, 0.f};
  const long vbase = ((long)(b * 16 + h) * 64) * SEQ;
#pragma unroll
  for (int kt = 0; kt < 2; ++kt) {
    bf16x8 ap[2], bvf[4];
#pragma unroll
    for (int mt = 0; mt < 2; ++mt)
      ap[mt] = *(const bf16x8*)(&Pw[mt * 16 + l15][kt * 32 + quad * 8]);
#pragma unroll
    for (int nt = 0; nt < 4; ++nt)
      bvf[nt] = *(const bf16x8*)(vT + vbase + (long)(nt * 16 + l15) * SEQ + n * 64 + kt * 32 + quad * 8);
#pragma unroll
    for (int mt = 0; mt < 2; ++mt)
#pragma unroll
      for (int nt = 0; nt < 4; ++nt)
        o[mt][nt] = __builtin_amdgcn_mfma_f32_16x16x32_bf16(bvf[nt], ap[mt], o[mt][nt], 0, 0, 0);
  }

  // --- store attended bf16 [token][h*64+d], u16x4 ---
#pragma unroll
  for (int mt = 0; mt < 2; ++mt)
#pragma unroll
    for (int nt = 0; nt < 4; ++nt) {
      const long row = qrow0 + mt * 16 + l15;
      const long col = cbase + nt * 16 + quad * 4;
      u16x4 pk;
      pk.x = f2b(o[mt][nt][0]);
      pk.y = f2b(o[mt][nt][1]);
      pk.z = f2b(o[mt][nt][2]);
      pk.w = f2b(o[mt][nt][3]);
      *(u16x4*)(attended + row * HID + col) = pk;
    }

  // --- head-mean partial: sum this block's 4 heads -> Psum[block][32][64] ---
  __syncthreads();
  float* pbase = Psum + (long)idx * 2048;
  for (int i = tid; i < 32 * 64; i += 256) {
    const int r = i >> 6, c = i & 63;
    float sacc = 0.f;
#pragma unroll
    for (int w = 0; w < 4; ++w) sacc += b2f(Plds[w][r][c]);
    pbase[i] = sacc;
  }
}

// ---------------- fused O-projection GEMM + attn-map expand ----------------
__global__ __launch_bounds__(256, 2) void gemm_o_expand(
    const u16* __restrict__ A, const u16* __restrict__ Bw,
    const float* __restrict__ bias, float* __restrict__ Cout,
    const float* __restrict__ Psum, float* __restrict__ attn) {
  __shared__ __align__(16) u16 As[2 * 128 * 32];
  __shared__ __align__(16) u16 Bs[2 * 128 * 32];

  const int tid = threadIdx.x;

  if (blockIdx.x >= 512) {
    // ---- expand path: 2048 blocks x 4096 float4 each ----
    const long e = blockIdx.x - 512;
    const long f0 = e * 4096;
#pragma unroll
    for (int it = 0; it < 16; ++it) {
      const long f = f0 + it * 256 + tid;              // float4 index into attn
      const int b = (int)(f >> 22);                    // 2^22 float4 per batch
      const int rem = (int)(f & ((1 << 22) - 1));
      const int row = rem >> 10;                       // 1024 float4 per row
      const int c4 = rem & 1023;
      const int n = row >> 6;
      float4 val = {0.f, 0.f, 0.f, 0.f};
      const int d4 = c4 - n * 16;                      // diag cols = [n*64, n*64+64)
      if ((unsigned)d4 < 16u) {
        const int r = row & 63;
        const int half = r >> 5, rr = r & 31;
        const long base = ((long)((b * 64 + n) * 8 + half)) * 2048 + rr * 64 + d4 * 4;
        float4 p0 = *(const float4*)(Psum + base);
        float4 p1 = *(const float4*)(Psum + base + 4096);
        float4 p2 = *(const float4*)(Psum + base + 8192);
        float4 p3 = *(const float4*)(Psum + base + 12288);
        val.x = (p0.x + p1.x + p2.x + p3.x) * (1.f / 16.f);
        val.y = (p0.y + p1.y + p2.y + p3.y) * (1.f / 16.f);
        val.z = (p0.z + p1.z + p2.z + p3.z) * (1.f / 16.f);
        val.w = (p0.w + p1.w + p2.w + p3.w) * (1.f / 16.f);
      }
      ((float4*)attn)[f] = val;
    }
    return;
  }

  const long brow = (long)(blockIdx.x >> 3) * 128;
  const long bcol = (long)(blockIdx.x & 7) * 128;
  gemm_core<1>(A, Bw, bias, Cout, As, Bs, brow, bcol);
}

extern "C" void kernel_launch(void* const* d_in, const int* in_sizes, int n_in,
                              void* d_out, int out_size, void* d_ws, size_t ws_size,
                              hipStream_t stream) {
  (void)in_sizes; (void)n_in; (void)out_size; (void)ws_size;
  const float* query = (const float*)d_in[0];
  const float* key   = (const float*)d_in[1];
  const float* value = (const float*)d_in[2];
  const float* Wq = (const float*)d_in[3];
  const float* bq = (const float*)d_in[4];
  const float* Wk = (const float*)d_in[5];
  const float* bk = (const float*)d_in[6];
  const float* Wv = (const float*)d_in[7];
  const float* bv = (const float*)d_in[8];
  const float* Wo = (const float*)d_in[9];
  const float* bo = (const float*)d_in[10];

  float* out  = (float*)d_out;
  float* attn = out + (size_t)BATCH * SEQ * HID;   // +8388608 floats

  char* ws = (char*)d_ws;
  const size_t MB = (size_t)1 << 20;
  // Workspace map (NO overlaps — vT is 16 MB: 88..104):
  //   xq 0-16 | xk 16-32 | xv 32-48 | wq/wk/wv/wo 48-56 | qp 56-72 | kp 72-88
  //   vT 88-104 | Psum 104-112
  u16* xq = (u16*)(ws + 0 * MB);    // later reused as 'attended'
  u16* xk = (u16*)(ws + 16 * MB);
  u16* xv = (u16*)(ws + 32 * MB);
  u16* wq = (u16*)(ws + 48 * MB);
  u16* wk = (u16*)(ws + 50 * MB);
  u16* wv = (u16*)(ws + 52 * MB);
  u16* wo = (u16*)(ws + 54 * MB);
  u16* qp = (u16*)(ws + 56 * MB);
  u16* kp = (u16*)(ws + 72 * MB);
  u16* vT = (u16*)(ws + 88 * MB);        // 16 MB: spans 88..104
  float* Psum = (float*)(ws + 104 * MB); // 8 MB: 104..112
  u16* att = xq;   // dead after gemm3 completes (attn_win runs strictly after)

  cvt_all<<<3584, 256, 0, stream>>>(query, key, value, Wq, Wk, Wv, Wo,
                                    xq, xk, xv, wq, wk, wv, wo);

  Gemm3Args ga;
  ga.A[0] = xq; ga.W[0] = wq; ga.bias[0] = bq; ga.C[0] = qp; ga.mode[0] = 0;
  ga.A[1] = xk; ga.W[1] = wk; ga.bias[1] = bk; ga.C[1] = kp; ga.mode[1] = 0;
  ga.A[2] = xv; ga.W[2] = wv; ga.bias[2] = bv; ga.C[2] = vT; ga.mode[2] = 2;
  dim3 g3(HID / 128, (BATCH * SEQ) / 128, 3);  // (8, 64, 3)
  gemm_bt_fused<<<g3, 256, 0, stream>>>(ga);

  attn_win<<<BATCH * 64 * 4 * 2, 256, 0, stream>>>(qp, kp, vT, att, Psum);

  gemm_o_expand<<<512 + 2048, 256, 0, stream>>>(att, wo, bo, out, Psum, attn);
}

// Round 8
// 390.946 us; speedup vs baseline: 1.0024x; 1.0024x over previous
//
#include <hip/hip_runtime.h>

typedef unsigned short u16;
typedef unsigned int u32;
typedef __attribute__((ext_vector_type(8))) short bf16x8;   // 8 bf16 in 4 VGPRs
typedef __attribute__((ext_vector_type(4))) float f32x4;
typedef __attribute__((ext_vector_type(4))) u16 u16x4;

typedef __attribute__((address_space(1))) unsigned int as1_u32;
typedef __attribute__((address_space(3))) unsigned int as3_u32;

#define SEQ 4096
#define HID 1024
#define NHEAD 16
#define BATCH 2

__device__ __forceinline__ u16 f2b(float f) {
  union { float f; u32 u; } v; v.f = f;
  u32 r = v.u + 0x7FFFu + ((v.u >> 16) & 1u);   // RNE
  return (u16)(r >> 16);
}

__device__ __forceinline__ float b2f(u16 b) {
  union { u32 u; float f; } v; v.u = ((u32)b) << 16;
  return v.f;
}

__device__ __forceinline__ void async_cp16(const void* g, void* l) {
  __builtin_amdgcn_global_load_lds((const as1_u32*)g, (as3_u32*)l, 16, 0, 0);
}

// ---------------- fp32 -> bf16 convert (all 7 tensors, one launch) ----------------
__global__ __launch_bounds__(256) void cvt_all(
    const float* __restrict__ q, const float* __restrict__ k, const float* __restrict__ v,
    const float* __restrict__ Wq, const float* __restrict__ Wk,
    const float* __restrict__ Wv, const float* __restrict__ Wo,
    u16* __restrict__ xq, u16* __restrict__ xk, u16* __restrict__ xv,
    u16* __restrict__ wq, u16* __restrict__ wk, u16* __restrict__ wv, u16* __restrict__ wo) {
  const int total = (3 << 21) + (4 << 18);   // 7,340,032 float4 groups
  for (int i = blockIdx.x * blockDim.x + threadIdx.x; i < total; i += gridDim.x * blockDim.x) {
    const float* src; u16* dst; int j;
    if (i < (3 << 21)) {
      const int sel = i >> 21; j = i & ((1 << 21) - 1);
      src = sel == 0 ? q : (sel == 1 ? k : v);
      dst = sel == 0 ? xq : (sel == 1 ? xk : xv);
    } else {
      const int ii = i - (3 << 21);
      const int sel = ii >> 18; j = ii & ((1 << 18) - 1);
      src = sel == 0 ? Wq : (sel == 1 ? Wk : (sel == 2 ? Wv : Wo));
      dst = sel == 0 ? wq : (sel == 1 ? wk : (sel == 2 ? wv : wo));
    }
    float4 f = ((const float4*)src)[j];
    u16x4 o; o.x = f2b(f.x); o.y = f2b(f.y); o.z = f2b(f.z); o.w = f2b(f.w);
    ((u16x4*)dst)[j] = o;
  }
}

// ---------------- GEMM core: C = A[8192x1024] * Bw[1024x1024]^T + bias ----------------
// BK=64 staged as two m97-style BK=32 panels per barrier round. Panel stride =
// 4096 u16 elements (128 rows x 32 cols).
// MODE 0: bf16 row-major out (operand-SWAPPED mfma -> vectorized row stores)
// MODE 1: fp32 row-major out (swapped, float4 stores)
// MODE 2: bf16 transposed out -> vT[(b*16+h)*64+d][token] (unswapped: regs = tokens)
template <int MODE>
__device__ __forceinline__ void gemm_core(
    const u16* __restrict__ A, const u16* __restrict__ Bw,
    const float* __restrict__ bias, void* __restrict__ Cout,
    u16* As, u16* Bs, long brow, long bcol) {
  const int K = HID, N = HID;
  const int tid = threadIdx.x;
  const int lane = tid & 63;
  const int wave = tid >> 6;
  const int l15 = lane & 15;
  const int quad = lane >> 4;
  const int wr = wave >> 1;
  const int wc = wave & 1;

  const int srow = lane >> 2;          // row within 16-row chunk (1 KB per cp16)
  const int scol = (lane & 3) * 8;     // bf16 elems (16B per lane)

  // 4 staging chunks per wave per matrix: j = (panel<<1)|sub
  const u16* Ag[4]; const u16* Bg[4]; u16* Al[4]; u16* Bl[4];
#pragma unroll
  for (int j = 0; j < 4; ++j) {
    const int sub = j & 1, pan = j >> 1;
    const long roff = (wave + 4 * sub) * 16 + srow;
    const long coff = pan * 32 + scol;
    Ag[j] = A + (brow + roff) * (long)K + coff;
    Bg[j] = Bw + (bcol + roff) * (long)K + coff;
    Al[j] = As + pan * 4096 + (wave + 4 * sub) * 512;
    Bl[j] = Bs + pan * 4096 + (wave + 4 * sub) * 512;
  }

  f32x4 acc[4][4];
#pragma unroll
  for (int i = 0; i < 4; ++i)
#pragma unroll
    for (int j = 0; j < 4; ++j) acc[i][j] = f32x4{0.f, 0.f, 0.f, 0.f};

  const u16* Afb = As + (wr * 64 + l15) * 32 + quad * 8;
  const u16* Bfb = Bs + (wc * 64 + l15) * 32 + quad * 8;

  for (int k0 = 0; k0 < K; k0 += 64) {
#pragma unroll
    for (int j = 0; j < 4; ++j) {
      async_cp16(Ag[j] + k0, Al[j]);
      async_cp16(Bg[j] + k0, Bl[j]);
    }
    __syncthreads();
#pragma unroll
    for (int kh = 0; kh < 2; ++kh) {
      bf16x8 af[4], bfv[4];
#pragma unroll
      for (int mt = 0; mt < 4; ++mt) af[mt] = *(const bf16x8*)(Afb + kh * 4096 + mt * 512);
#pragma unroll
      for (int nt = 0; nt < 4; ++nt) bfv[nt] = *(const bf16x8*)(Bfb + kh * 4096 + nt * 512);
#pragma unroll
      for (int mt = 0; mt < 4; ++mt)
#pragma unroll
        for (int nt = 0; nt < 4; ++nt) {
          if (MODE == 2)
            acc[mt][nt] = __builtin_amdgcn_mfma_f32_16x16x32_bf16(af[mt], bfv[nt], acc[mt][nt], 0, 0, 0);
          else  // swapped: D^T -> cols(N) on quad/reg, rows(M) on l15
            acc[mt][nt] = __builtin_amdgcn_mfma_f32_16x16x32_bf16(bfv[nt], af[mt], acc[mt][nt], 0, 0, 0);
        }
    }
    __syncthreads();
  }

  const long crow0 = brow + wr * 64;
  const long ccol0 = bcol + wc * 64;

  if (MODE == 2) {
    // acc[mt][nt][r] = C[token = crow0+mt*16+quad*4+r][hid = ccol0+nt*16+l15]
#pragma unroll
    for (int nt = 0; nt < 4; ++nt) {
      const long col = ccol0 + nt * 16 + l15;
      const float bv = bias[col];
#pragma unroll
      for (int mt = 0; mt < 4; ++mt) {
        const long tokbase = crow0 + mt * 16 + quad * 4;  // 4 consecutive tokens
        const long b = tokbase >> 12;
        const long tok = tokbase & 4095;
        u16x4 pk;
        pk.x = f2b(acc[mt][nt][0] + bv);
        pk.y = f2b(acc[mt][nt][1] + bv);
        pk.z = f2b(acc[mt][nt][2] + bv);
        pk.w = f2b(acc[mt][nt][3] + bv);
        *(u16x4*)((u16*)Cout + (b * 1024 + col) * (long)SEQ + tok) = pk;
      }
    }
  } else {
    // swapped: acc[mt][nt][r] = C[crow0+mt*16+l15][ccol0+nt*16+quad*4+r]
#pragma unroll
    for (int nt = 0; nt < 4; ++nt) {
      const long colb = ccol0 + nt * 16 + quad * 4;
      const float4 b4 = *(const float4*)(bias + colb);
#pragma unroll
      for (int mt = 0; mt < 4; ++mt) {
        const long row = crow0 + mt * 16 + l15;
        if (MODE == 1) {
          float4 v;
          v.x = acc[mt][nt][0] + b4.x;
          v.y = acc[mt][nt][1] + b4.y;
          v.z = acc[mt][nt][2] + b4.z;
          v.w = acc[mt][nt][3] + b4.w;
          *(float4*)((float*)Cout + row * (long)N + colb) = v;
        } else {
          u16x4 pk;
          pk.x = f2b(acc[mt][nt][0] + b4.x);
          pk.y = f2b(acc[mt][nt][1] + b4.y);
          pk.z = f2b(acc[mt][nt][2] + b4.z);
          pk.w = f2b(acc[mt][nt][3] + b4.w);
          *(u16x4*)((u16*)Cout + row * (long)N + colb) = pk;
        }
      }
    }
  }
}

struct Gemm3Args {
  const u16* A[3]; const u16* W[3]; const float* bias[3]; void* C[3]; int mode[3];
};

// z=0..2: projection GEMMs. z=3: zero the 134 MB attn map in the MFMA shadow
// (dispatched last -> backfills CU slots as GEMM blocks drain; diag blocks get
// real values later from gemm_o_expand, which runs strictly after).
__global__ __launch_bounds__(256, 2) void gemm_bt_fused(Gemm3Args ga, float* __restrict__ attn) {
  __shared__ __align__(16) u16 As[2 * 128 * 32];   // 16 KB (2 panels of 4096 elems)
  __shared__ __align__(16) u16 Bs[2 * 128 * 32];   // 16 KB
  const int z = blockIdx.z;
  const int tid = threadIdx.x;

  if (z == 3) {
    const long e = (long)blockIdx.y * 8 + blockIdx.x;   // 0..511
    float4* dst = (float4*)attn + e * 16384;            // 512 x 16384 = 8.39M float4
#pragma unroll
    for (int it = 0; it < 64; ++it)
      dst[it * 256 + tid] = float4{0.f, 0.f, 0.f, 0.f};
    return;
  }

  const long brow = (long)blockIdx.y * 128;
  const long bcol = (long)blockIdx.x * 128;
  if (ga.mode[z] == 2)
    gemm_core<2>(ga.A[z], ga.W[z], ga.bias[z], ga.C[z], As, Bs, brow, bcol);
  else
    gemm_core<0>(ga.A[z], ga.W[z], ga.bias[z], ga.C[z], As, Bs, brow, bcol);
}

// ---------------- windowed attention ----------------
// block = (b, window, head-group of 4, row-half). wave = one head, 32 query rows.
// grid = 2*64*4*2 = 1024 blocks. Swapped-operand MFMA throughout.
__global__ __launch_bounds__(256, 4) void attn_win(
    const u16* __restrict__ qp, const u16* __restrict__ kp,
    const u16* __restrict__ vT, u16* __restrict__ attended,
    float* __restrict__ Psum) {
  __shared__ __align__(16) u16 Plds[4][32][72];    // per-wave P (bf16) [query][key]

  const int tid = threadIdx.x;
  const int lane = tid & 63;
  const int wave = tid >> 6;
  const int l15 = lane & 15;
  const int quad = lane >> 4;

  const int idx = blockIdx.x;          // (((b*64+n)*4)+hg)*2 + half
  const int half = idx & 1;
  const int hg = (idx >> 1) & 3;
  const int wn = idx >> 3;
  const int b = wn >> 6;
  const int n = wn & 63;
  const int h = hg * 4 + wave;

  const long qrow0 = (long)b * SEQ + (long)n * 64 + half * 32;  // 32 query rows
  const long krow0 = (long)b * SEQ + (long)n * 64;              // all 64 key rows
  const long cbase = (long)h * 64;

  u16(*Pw)[72] = Plds[wave];

  // --- S' = (K Q^T): s[mt][nt][reg]: key = nt*16+quad*4+reg, query = mt*16+l15 ---
  f32x4 s[2][4];
#pragma unroll
  for (int i = 0; i < 2; ++i)
#pragma unroll
    for (int j = 0; j < 4; ++j) s[i][j] = f32x4{0.f, 0.f, 0.f, 0.f};
#pragma unroll
  for (int kt = 0; kt < 2; ++kt) {
    bf16x8 aq[2], bkf[4];
#pragma unroll
    for (int mt = 0; mt < 2; ++mt)
      aq[mt] = *(const bf16x8*)(qp + (qrow0 + mt * 16 + l15) * HID + cbase + kt * 32 + quad * 8);
#pragma unroll
    for (int nt = 0; nt < 4; ++nt)
      bkf[nt] = *(const bf16x8*)(kp + (krow0 + nt * 16 + l15) * HID + cbase + kt * 32 + quad * 8);
#pragma unroll
    for (int mt = 0; mt < 2; ++mt)
#pragma unroll
      for (int nt = 0; nt < 4; ++nt)
        s[mt][nt] = __builtin_amdgcn_mfma_f32_16x16x32_bf16(bkf[nt], aq[mt], s[mt][nt], 0, 0, 0);
  }

  // --- softmax over 64 keys: 16 in-lane values (nt x reg) + quad reduce ---
#pragma unroll
  for (int mt = 0; mt < 2; ++mt) {
    float m = -1e30f;
#pragma unroll
    for (int nt = 0; nt < 4; ++nt)
#pragma unroll
      for (int r = 0; r < 4; ++r) { s[mt][nt][r] *= 0.125f; m = fmaxf(m, s[mt][nt][r]); }
    m = fmaxf(m, __shfl_xor(m, 16));
    m = fmaxf(m, __shfl_xor(m, 32));
    float sum = 0.f;
#pragma unroll
    for (int nt = 0; nt < 4; ++nt)
#pragma unroll
      for (int r = 0; r < 4; ++r) { float e = __expf(s[mt][nt][r] - m); s[mt][nt][r] = e; sum += e; }
    sum += __shfl_xor(sum, 16);
    sum += __shfl_xor(sum, 32);
    const float inv = 1.f / sum;
#pragma unroll
    for (int nt = 0; nt < 4; ++nt)
#pragma unroll
      for (int r = 0; r < 4; ++r) s[mt][nt][r] *= inv;
  }

  // --- stash P (bf16) [query][key], vectorized u16x4 writes ---
#pragma unroll
  for (int mt = 0; mt < 2; ++mt)
#pragma unroll
    for (int nt = 0; nt < 4; ++nt) {
      u16x4 pk;
      pk.x = f2b(s[mt][nt][0]);
      pk.y = f2b(s[mt][nt][1]);
      pk.z = f2b(s[mt][nt][2]);
      pk.w = f2b(s[mt][nt][3]);
      *(u16x4*)(&Pw[mt * 16 + l15][nt * 16 + quad * 4]) = pk;
    }

  // --- O' = (V^T P^T): o[mt][nt][reg]: d = nt*16+quad*4+reg, token = mt*16+l15 ---
  f32x4 o[2][4];
#pragma unroll
  for (int i = 0; i < 2; ++i)
#pragma unroll
    for (int j = 0; j < 4; ++j) o[i][j] = f32x4{0.f, 0.f, 0.f, 0.f};
  const long vbase = ((long)(b * 16 + h) * 64) * SEQ;
#pragma unroll
  for (int kt = 0; kt < 2; ++kt) {
    bf16x8 ap[2], bvf[4];
#pragma unroll
    for (int mt = 0; mt < 2; ++mt)
      ap[mt] = *(const bf16x8*)(&Pw[mt * 16 + l15][kt * 32 + quad * 8]);
#pragma unroll
    for (int nt = 0; nt < 4; ++nt)
      bvf[nt] = *(const bf16x8*)(vT + vbase + (long)(nt * 16 + l15) * SEQ + n * 64 + kt * 32 + quad * 8);
#pragma unroll
    for (int mt = 0; mt < 2; ++mt)
#pragma unroll
      for (int nt = 0; nt < 4; ++nt)
        o[mt][nt] = __builtin_amdgcn_mfma_f32_16x16x32_bf16(bvf[nt], ap[mt], o[mt][nt], 0, 0, 0);
  }

  // --- store attended bf16 [token][h*64+d], u16x4 ---
#pragma unroll
  for (int mt = 0; mt < 2; ++mt)
#pragma unroll
    for (int nt = 0; nt < 4; ++nt) {
      const long row = qrow0 + mt * 16 + l15;
      const long col = cbase + nt * 16 + quad * 4;
      u16x4 pk;
      pk.x = f2b(o[mt][nt][0]);
      pk.y = f2b(o[mt][nt][1]);
      pk.z = f2b(o[mt][nt][2]);
      pk.w = f2b(o[mt][nt][3]);
      *(u16x4*)(attended + row * HID + col) = pk;
    }

  // --- head-mean partial: sum this block's 4 heads -> Psum[block][32][64] ---
  __syncthreads();
  float* pbase = Psum + (long)idx * 2048;
  for (int i = tid; i < 32 * 64; i += 256) {
    const int r = i >> 6, c = i & 63;
    float sacc = 0.f;
#pragma unroll
    for (int w = 0; w < 4; ++w) sacc += b2f(Plds[w][r][c]);
    pbase[i] = sacc;
  }
}

// ---------------- fused O-projection GEMM + diagonal write ----------------
// blocks 0..511: out = att * Wo^T + bo (fp32). blocks 512..639: write ONLY the
// 128 diagonal 64x64 blocks of the attn map (head mean from Psum); the zeros
// were already written by gemm_bt_fused's z=3 slice.
__global__ __launch_bounds__(256, 2) void gemm_o_expand(
    const u16* __restrict__ A, const u16* __restrict__ Bw,
    const float* __restrict__ bias, float* __restrict__ Cout,
    const float* __restrict__ Psum, float* __restrict__ attn) {
  __shared__ __align__(16) u16 As[2 * 128 * 32];
  __shared__ __align__(16) u16 Bs[2 * 128 * 32];

  const int tid = threadIdx.x;

  if (blockIdx.x >= 512) {
    const int e = blockIdx.x - 512;          // 0..127 = (b, n)
    const int b = e >> 6, n = e & 63;
    float* obase = attn + (long)b * SEQ * SEQ + (long)n * 64 * SEQ + (long)n * 64;
    const long pb = (long)((b * 64 + n) * 8) * 2048;
#pragma unroll
    for (int it = 0; it < 4; ++it) {
      const int li = it * 256 + tid;         // 0..1023: 64 rows x 16 float4
      const int r = li >> 4, c4 = li & 15;
      const int half = r >> 5, rr = r & 31;
      const long base = pb + half * 2048 + rr * 64 + c4 * 4;
      float4 p0 = *(const float4*)(Psum + base);
      float4 p1 = *(const float4*)(Psum + base + 4096);
      float4 p2 = *(const float4*)(Psum + base + 8192);
      float4 p3 = *(const float4*)(Psum + base + 12288);
      float4 val;
      val.x = (p0.x + p1.x + p2.x + p3.x) * (1.f / 16.f);
      val.y = (p0.y + p1.y + p2.y + p3.y) * (1.f / 16.f);
      val.z = (p0.z + p1.z + p2.z + p3.z) * (1.f / 16.f);
      val.w = (p0.w + p1.w + p2.w + p3.w) * (1.f / 16.f);
      *(float4*)(obase + (long)r * SEQ + c4 * 4) = val;
    }
    return;
  }

  const long brow = (long)(blockIdx.x >> 3) * 128;
  const long bcol = (long)(blockIdx.x & 7) * 128;
  gemm_core<1>(A, Bw, bias, Cout, As, Bs, brow, bcol);
}

extern "C" void kernel_launch(void* const* d_in, const int* in_sizes, int n_in,
                              void* d_out, int out_size, void* d_ws, size_t ws_size,
                              hipStream_t stream) {
  (void)in_sizes; (void)n_in; (void)out_size; (void)ws_size;
  const float* query = (const float*)d_in[0];
  const float* key   = (const float*)d_in[1];
  const float* value = (const float*)d_in[2];
  const float* Wq = (const float*)d_in[3];
  const float* bq = (const float*)d_in[4];
  const float* Wk = (const float*)d_in[5];
  const float* bk = (const float*)d_in[6];
  const float* Wv = (const float*)d_in[7];
  const float* bv = (const float*)d_in[8];
  const float* Wo = (const float*)d_in[9];
  const float* bo = (const float*)d_in[10];

  float* out  = (float*)d_out;
  float* attn = out + (size_t)BATCH * SEQ * HID;   // +8388608 floats

  char* ws = (char*)d_ws;
  const size_t MB = (size_t)1 << 20;
  // Workspace map (NO overlaps — vT is 16 MB: 88..104):
  //   xq 0-16 | xk 16-32 | xv 32-48 | wq/wk/wv/wo 48-56 | qp 56-72 | kp 72-88
  //   vT 88-104 | Psum 104-112
  u16* xq = (u16*)(ws + 0 * MB);    // later reused as 'attended'
  u16* xk = (u16*)(ws + 16 * MB);
  u16* xv = (u16*)(ws + 32 * MB);
  u16* wq = (u16*)(ws + 48 * MB);
  u16* wk = (u16*)(ws + 50 * MB);
  u16* wv = (u16*)(ws + 52 * MB);
  u16* wo = (u16*)(ws + 54 * MB);
  u16* qp = (u16*)(ws + 56 * MB);
  u16* kp = (u16*)(ws + 72 * MB);
  u16* vT = (u16*)(ws + 88 * MB);        // 16 MB: spans 88..104
  float* Psum = (float*)(ws + 104 * MB); // 8 MB: 104..112
  u16* att = xq;   // dead after gemm3 completes (attn_win runs strictly after)

  cvt_all<<<3584, 256, 0, stream>>>(query, key, value, Wq, Wk, Wv, Wo,
                                    xq, xk, xv, wq, wk, wv, wo);

  Gemm3Args ga;
  ga.A[0] = xq; ga.W[0] = wq; ga.bias[0] = bq; ga.C[0] = qp; ga.mode[0] = 0;
  ga.A[1] = xk; ga.W[1] = wk; ga.bias[1] = bk; ga.C[1] = kp; ga.mode[1] = 0;
  ga.A[2] = xv; ga.W[2] = wv; ga.bias[2] = bv; ga.C[2] = vT; ga.mode[2] = 2;
  dim3 g4(HID / 128, (BATCH * SEQ) / 128, 4);  // (8, 64, 4): z=3 zeros attn map
  gemm_bt_fused<<<g4, 256, 0, stream>>>(ga, attn);

  attn_win<<<BATCH * 64 * 4 * 2, 256, 0, stream>>>(qp, kp, vT, att, Psum);

  gemm_o_expand<<<512 + 128, 256, 0, stream>>>(att, wo, bo, out, Psum, attn);
}